// Round 8
// baseline (913.831 us; speedup 1.0000x reference)
//
#include <hip/hip_runtime.h>
#include <cstdint>

#define NN 100000
#define EE 1600000
#define GG 64
#define FIN 128
#define HC 256      // H*C for layer 1
#define NC 10

typedef short v8s __attribute__((ext_vector_type(8)));
typedef float v4f __attribute__((ext_vector_type(4)));

static __device__ __forceinline__ float lrelu(float x) { return x > 0.f ? x : 0.2f * x; }
static __device__ __forceinline__ float bf2f(unsigned short b) {
  return __uint_as_float(((unsigned int)b) << 16);
}
static __device__ __forceinline__ unsigned short f2bf(float f) {
  unsigned int u = __float_as_uint(f);
  unsigned int r = (u + 0x7FFFu + ((u >> 16) & 1u)) >> 16;
  return (unsigned short)r;
}
static __device__ __forceinline__ void unpack2(unsigned int u, float& f0, float& f1) {
  f0 = __uint_as_float(u << 16);          // even channel (lo ushort)
  f1 = __uint_as_float(u & 0xFFFF0000u);  // odd channel (hi ushort)
}

// ---------------- utility ----------------
__global__ void k_zero(unsigned int* __restrict__ p, int n) {
  int i = blockIdx.x * 256 + threadIdx.x;
  if (i < n) p[i] = 0u;
}

// ---------------- prep: W1 -> bf16 transposed [n][k]; W2 -> fp32 transposed [c][k] ----------------
__global__ void k_prep(const float* __restrict__ W1, const float* __restrict__ W2,
                       unsigned short* __restrict__ W1tg, float* __restrict__ W2t) {
  const int b = blockIdx.x, t = threadIdx.x;
  if (b < 256) {
    if (t < 128) W1tg[b * 128 + t] = f2bf(W1[t * HC + b]);
  } else {
    const int c = b - 256;              // 0..31
    W2t[c * 256 + t] = W2[t * 32 + c];
  }
}

// ---------------- GEMM1 (bf16 MFMA, LDS-free) + fused scores1 ----------------
// grid (1563, 2): 64 rows x 128-col half per block; 4 waves x 16 rows.
// B-fragments read directly from pre-transposed global W1tg (L2-hot, 64KB).
__global__ __launch_bounds__(256) void k_gemm1(const float* __restrict__ x,
                                               const unsigned short* __restrict__ W1tg,
                                               const float* __restrict__ att_src1,
                                               const float* __restrict__ att_dst1,
                                               unsigned short* __restrict__ h1b,
                                               float* __restrict__ as1,
                                               float* __restrict__ ad1) {
  const int t = threadIdx.x;
  const int m0 = blockIdx.x * 64;
  const int n0 = blockIdx.y * 128;
  const int hb = blockIdx.y * 4;       // head base of this column half
  const int lane = t & 63;
  const int wm = t >> 6;               // wave -> m sub-tile
  const int ml = lane & 15;
  const int quad = lane >> 4;
  int row = m0 + wm * 16 + ml; if (row >= NN) row = NN - 1;
  v4f acc[8];
#pragma unroll
  for (int tt = 0; tt < 8; ++tt) acc[tt] = (v4f){0.f, 0.f, 0.f, 0.f};
#pragma unroll
  for (int kk = 0; kk < 4; ++kk) {
    const int k0 = kk * 32 + quad * 8;
    float4 lo = *(const float4*)(x + (size_t)row * FIN + k0);
    float4 hi = *(const float4*)(x + (size_t)row * FIN + k0 + 4);
    v8s a;
    a[0] = (short)f2bf(lo.x); a[1] = (short)f2bf(lo.y);
    a[2] = (short)f2bf(lo.z); a[3] = (short)f2bf(lo.w);
    a[4] = (short)f2bf(hi.x); a[5] = (short)f2bf(hi.y);
    a[6] = (short)f2bf(hi.z); a[7] = (short)f2bf(hi.w);
#pragma unroll
    for (int tt = 0; tt < 8; ++tt) {
      v8s b = *(const v8s*)(W1tg + (size_t)(n0 + tt * 16 + ml) * FIN + k0);
      acc[tt] = __builtin_amdgcn_mfma_f32_16x16x32_bf16(a, b, acc[tt], 0, 0, 0);
    }
  }
  // h1b store (C layout: row=quad*4+r, col=tt*16+ml)
#pragma unroll
  for (int tt = 0; tt < 8; ++tt) {
#pragma unroll
    for (int r = 0; r < 4; ++r) {
      int rg = m0 + wm * 16 + quad * 4 + r;
      if (rg < NN) h1b[(size_t)rg * HC + n0 + tt * 16 + ml] = f2bf(acc[tt][r]);
    }
  }
  // fused scores1: 4 heads of this half; lane partials over its 8 columns
  float ps[4][4], pd[4][4];
#pragma unroll
  for (int i = 0; i < 4; ++i)
#pragma unroll
    for (int r = 0; r < 4; ++r) { ps[i][r] = 0.f; pd[i][r] = 0.f; }
#pragma unroll
  for (int i = 0; i < 4; ++i) {
#pragma unroll
    for (int half = 0; half < 2; ++half) {
      const int tt = 2 * i + half;
      const float a_s = att_src1[(hb + i) * 32 + half * 16 + ml];
      const float a_d = att_dst1[(hb + i) * 32 + half * 16 + ml];
#pragma unroll
      for (int r = 0; r < 4; ++r) {
        ps[i][r] += acc[tt][r] * a_s;
        pd[i][r] += acc[tt][r] * a_d;
      }
    }
  }
#pragma unroll
  for (int i = 0; i < 4; ++i) {
#pragma unroll
    for (int r = 0; r < 4; ++r) {
      float s = ps[i][r], d = pd[i][r];
      s += __shfl_xor(s, 1, 64); s += __shfl_xor(s, 2, 64);
      s += __shfl_xor(s, 4, 64); s += __shfl_xor(s, 8, 64);
      d += __shfl_xor(d, 1, 64); d += __shfl_xor(d, 2, 64);
      d += __shfl_xor(d, 4, 64); d += __shfl_xor(d, 8, 64);
      ps[i][r] = s; pd[i][r] = d;
    }
  }
  if (ml == 0) {
#pragma unroll
    for (int r = 0; r < 4; ++r) {
      int rg = m0 + wm * 16 + quad * 4 + r;
      if (rg < NN) {
#pragma unroll
        for (int i = 0; i < 4; ++i) {
          as1[rg * 8 + hb + i] = ps[i][r];
          ad1[rg * 8 + hb + i] = pd[i][r];
        }
      }
    }
  }
}

// ---------------- CSR build ----------------
__global__ void k_count(const int* __restrict__ ei, int* __restrict__ counts) {
  int e = blockIdx.x * 256 + threadIdx.x;
  if (e < EE) atomicAdd(&counts[ei[EE + e]], 1);
}

__global__ void k_scan1(const int* __restrict__ counts, int* __restrict__ offs,
                        int* __restrict__ bsums) {
  __shared__ int s[256];
  const int t = threadIdx.x;
  const int i = blockIdx.x * 256 + t;
  int v = (i < NN) ? counts[i] : 0;
  s[t] = v;
  __syncthreads();
  for (int off = 1; off < 256; off <<= 1) {
    int tv = (t >= off) ? s[t - off] : 0;
    __syncthreads();
    s[t] += tv;
    __syncthreads();
  }
  if (i < NN) offs[i] = s[t] - v;
  if (t == 255) bsums[blockIdx.x] = s[255];
}

__global__ void k_scan2(int* __restrict__ bsums, int nb) {
  __shared__ int s[512];
  const int t = threadIdx.x;
  int v = (t < nb) ? bsums[t] : 0;
  s[t] = v;
  __syncthreads();
  for (int off = 1; off < 512; off <<= 1) {
    int tv = (t >= off) ? s[t - off] : 0;
    __syncthreads();
    s[t] += tv;
    __syncthreads();
  }
  if (t < nb) bsums[t] = s[t] - v;
}

__global__ void k_scan3(int* __restrict__ offs, const int* __restrict__ bsums,
                        int* __restrict__ cursor) {
  const int i = blockIdx.x * 256 + threadIdx.x;
  if (i < NN) {
    int v = offs[i] + bsums[i >> 8];
    offs[i] = v;
    cursor[i] = v;
  }
  if (i == 0) offs[NN] = EE;
}

// ---------------- scatter + fused layer-1 edge weights ----------------
__global__ void k_scatter(const int* __restrict__ ei, int* __restrict__ cursor,
                          const float* __restrict__ as1, const float* __restrict__ ad1,
                          int* __restrict__ esrc, float* __restrict__ wt) {
  int e = blockIdx.x * 256 + threadIdx.x;
  if (e < EE) {
    int s = ei[e];
    int d = ei[EE + e];
    int p = atomicAdd(&cursor[d], 1);
    esrc[p] = s;
    float4 a0 = *(const float4*)(as1 + s * 8);
    float4 a1 = *(const float4*)(as1 + s * 8 + 4);
    float4 b0 = *(const float4*)(ad1 + d * 8);
    float4 b1 = *(const float4*)(ad1 + d * 8 + 4);
    float4 r0, r1;
    r0.x = __expf(lrelu(a0.x + b0.x)); r0.y = __expf(lrelu(a0.y + b0.y));
    r0.z = __expf(lrelu(a0.z + b0.z)); r0.w = __expf(lrelu(a0.w + b0.w));
    r1.x = __expf(lrelu(a1.x + b1.x)); r1.y = __expf(lrelu(a1.y + b1.y));
    r1.z = __expf(lrelu(a1.z + b1.z)); r1.w = __expf(lrelu(a1.w + b1.w));
    *(float4*)(wt + (size_t)p * 8) = r0;
    *(float4*)(wt + (size_t)p * 8 + 4) = r1;
  }
}

// ---------------- fused agg1 + bias + ELU + GEMM2 row + scores2 ----------------
// 256 threads = 4 waves = 4 nodes per block; each WAVE owns one node end to
// end. NO __syncthreads anywhere: LDS (wl, sv) is wave-private and LDS ops
// within a wave complete in order. Gather: full 512B rows (64 lanes x uint2),
// weights precomputed in wt. GEMM2 uses pre-transposed W2t (L1-hot).
__global__ __launch_bounds__(256) void k_agg1(const unsigned short* __restrict__ h1b,
                                              const float* __restrict__ as1,
                                              const float* __restrict__ ad1,
                                              const int* __restrict__ offs,
                                              const int* __restrict__ esrc,
                                              const float* __restrict__ wt,
                                              const float* __restrict__ b1,
                                              const float* __restrict__ W2t,
                                              const float* __restrict__ att_src2,
                                              const float* __restrict__ att_dst2,
                                              unsigned short* __restrict__ h2b,
                                              float* __restrict__ as2,
                                              float* __restrict__ ad2) {
  __shared__ float wl[4][64][8];   // per-wave edge weights (8KB)
  __shared__ float sv[4][256];     // per-wave out1 row (4KB)
  const int t = threadIdx.x;
  const int lane = t & 63;
  const int w = t >> 6;
  const int n = blockIdx.x * 4 + w;      // NN = 25000*4 exactly
  const int head = lane >> 3;            // channels 4*lane.. live in head lane>>3
  const int start = offs[n], end = offs[n + 1];
  const uint2* h1u2 = (const uint2*)h1b;
  float (*wlw)[8] = wl[w];

  // self loop
  float w0 = __expf(lrelu(as1[n * 8 + head] + ad1[n * 8 + head]));
  float z = w0;
  float acc0, acc1, acc2, acc3;
  {
    uint2 q = h1u2[(size_t)n * 64 + lane];
    float f0, f1, f2, f3; unpack2(q.x, f0, f1); unpack2(q.y, f2, f3);
    acc0 = w0 * f0; acc1 = w0 * f1; acc2 = w0 * f2; acc3 = w0 * f3;
  }

  for (int base = start; base < end; base += 64) {
    const int cnt = min(64, end - base);
    int sreg = 0;
    if (lane < cnt) {
      sreg = esrc[base + lane];
      float4 r0 = *(const float4*)(wt + (size_t)(base + lane) * 8);
      float4 r1 = *(const float4*)(wt + (size_t)(base + lane) * 8 + 4);
      *(float4*)&wlw[lane][0] = r0;
      *(float4*)&wlw[lane][4] = r1;
    }
#pragma unroll 8
    for (int j2 = 0; j2 < cnt; ++j2) {
      int sj = __builtin_amdgcn_readlane(sreg, j2);   // uniform -> SGPR base
      uint2 q = h1u2[(size_t)sj * 64 + lane];         // full 512B row per wave
      float wv = wlw[j2][head];
      float f0, f1, f2, f3; unpack2(q.x, f0, f1); unpack2(q.y, f2, f3);
      z += wv;
      acc0 += wv * f0; acc1 += wv * f1; acc2 += wv * f2; acc3 += wv * f3;
    }
  }

  // normalize + bias + ELU -> sv (wave-private; no barrier needed)
  {
    const float zi = 1.0f / (z + 1e-16f);
    float4 bb = *(const float4*)(b1 + 4 * lane);
    float v0 = acc0 * zi + bb.x;
    float v1 = acc1 * zi + bb.y;
    float v2 = acc2 * zi + bb.z;
    float v3 = acc3 * zi + bb.w;
    v0 = v0 > 0.f ? v0 : (__expf(v0) - 1.0f);
    v1 = v1 > 0.f ? v1 : (__expf(v1) - 1.0f);
    v2 = v2 > 0.f ? v2 : (__expf(v2) - 1.0f);
    v3 = v3 > 0.f ? v3 : (__expf(v3) - 1.0f);
    *(float4*)&sv[w][4 * lane] = make_float4(v0, v1, v2, v3);
  }
  // GEMM2 row: c = lane&31, k-half = lane>>5; W2t[c][k] contiguous in k
  {
    const int c = lane & 31, kh = lane >> 5;
    const float* svw = &sv[w][kh * 128];
    const float* wtp = W2t + c * 256 + kh * 128;
    float p = 0.f;
#pragma unroll 8
    for (int k4 = 0; k4 < 128; k4 += 4) {
      float4 s4 = *(const float4*)&svw[k4];
      float4 w4 = *(const float4*)&wtp[k4];
      p += s4.x * w4.x + s4.y * w4.y + s4.z * w4.z + s4.w * w4.w;
    }
    p += __shfl_xor(p, 32, 64);          // combine k-halves; both halves now equal
    const float hv = p;
    if (lane < 32) h2b[(size_t)n * 32 + lane] = f2bf(hv);
    float ps = hv * att_src2[c];
    float pd = hv * att_dst2[c];
#pragma unroll
    for (int m = 16; m >= 1; m >>= 1) {
      ps += __shfl_xor(ps, m, 64);
      pd += __shfl_xor(pd, m, 64);
    }
    if (lane == 0) { as2[n] = ps; ad2[n] = pd; }
  }
}

// ---------------- agg2: softmax-weighted sum -> dense h3 ----------------
__global__ __launch_bounds__(256) void k_agg2(const unsigned short* __restrict__ h2b,
                                              const float* __restrict__ as2,
                                              const float* __restrict__ ad2,
                                              const int* __restrict__ offs,
                                              const int* __restrict__ esrc,
                                              const float* __restrict__ b2,
                                              float* __restrict__ h3) {
  const int t = threadIdx.x;
  const int g = t >> 5, c = t & 31;
  const int n = blockIdx.x * 8 + g;
  const int sbase = t & 32;
  const int start = offs[n], end = offs[n + 1];
  const float adn = ad2[n];
  float w0 = __expf(lrelu(as2[n] + adn));
  float z = w0;
  float acc = w0 * bf2f(h2b[(size_t)n * 32 + c]);
  for (int base = start; base < end; base += 32) {
    const int cnt = min(32, end - base);
    int s_reg = 0; float w_reg = 0.f;
    if (c < cnt) {
      s_reg = esrc[base + c];
      w_reg = __expf(lrelu(as2[s_reg] + adn));
    }
#pragma unroll 8
    for (int j = 0; j < cnt; ++j) {
      int sj = __shfl(s_reg, sbase + j, 64);
      float wj = __shfl(w_reg, sbase + j, 64);
      z += wj;
      acc += wj * bf2f(h2b[(size_t)sj * 32 + c]);
    }
  }
  h3[(size_t)n * 32 + c] = acc / (z + 1e-16f) + b2[c];
}

// ---------------- pool + final linear (fused) ----------------
__global__ __launch_bounds__(256) void k_poolfin(const float* __restrict__ h3,
                                                 const int* __restrict__ batch,
                                                 const float* __restrict__ Wlin,
                                                 const float* __restrict__ blin,
                                                 float* __restrict__ out) {
  __shared__ int bounds[2];
  __shared__ float red[8][33];
  __shared__ float mean[32];
  const int g = blockIdx.x;
  const int t = threadIdx.x;
  if (t < 2) {
    int target = g + t;
    int lo = 0, hi = NN;
    while (lo < hi) { int mid = (lo + hi) >> 1; if (batch[mid] < target) lo = mid + 1; else hi = mid; }
    bounds[t] = lo;
  }
  __syncthreads();
  const int lo = bounds[0], hi = bounds[1];
  const int rr = t >> 5, c = t & 31;
  float a = 0.f;
  for (int r = lo + rr; r < hi; r += 8) a += h3[(size_t)r * 32 + c];
  red[rr][c] = a;
  __syncthreads();
  if (rr == 0) {
    float s = 0.f;
#pragma unroll
    for (int i = 0; i < 8; ++i) s += red[i][c];
    float ct = (float)(hi - lo);
    ct = ct > 1.f ? ct : 1.f;
    mean[c] = s / ct;
  }
  __syncthreads();
  if (t < NC) {
    float acc = 0.f;
#pragma unroll
    for (int cc = 0; cc < 32; ++cc) acc += mean[cc] * Wlin[cc * NC + t];
    out[g * NC + t] = acc + blin[t];
  }
}

extern "C" void kernel_launch(void* const* d_in, const int* in_sizes, int n_in,
                              void* d_out, int out_size, void* d_ws, size_t ws_size,
                              hipStream_t stream) {
  const float* x        = (const float*)d_in[0];
  const int*   ei       = (const int*)d_in[1];
  const int*   batch    = (const int*)d_in[2];
  const float* W1       = (const float*)d_in[3];
  const float* att_src1 = (const float*)d_in[4];
  const float* att_dst1 = (const float*)d_in[5];
  const float* b1       = (const float*)d_in[6];
  const float* W2       = (const float*)d_in[7];
  const float* att_src2 = (const float*)d_in[8];
  const float* att_dst2 = (const float*)d_in[9];
  const float* b2       = (const float*)d_in[10];
  const float* Wlin     = (const float*)d_in[11];
  const float* blin     = (const float*)d_in[12];
  float* out = (float*)d_out;
  char* ws = (char*)d_ws;

  // workspace layout (bytes); peak ~124 MB (wt dead after agg1 -> h3 overlay)
  unsigned short* h1b  = (unsigned short*)(ws + 0);        // 51,200,000
  float* as1    = (float*)(ws + 51200000);                 // 3,200,000
  float* ad1    = (float*)(ws + 54400000);                 // 3,200,000
  int* counts   = (int*)(ws + 57600000);                   // 400,000
  int* offs     = (int*)(ws + 58000000);                   // 400,004 (+pad)
  int* cursor   = (int*)(ws + 58400256);                   // 400,000
  int* esrc     = (int*)(ws + 58800256);                   // 6,400,000
  int* bsums    = (int*)(ws + 65200256);                   // 1,564 (+pad)
  unsigned short* h2b = (unsigned short*)(ws + 65202048);  // 6,400,000
  float* as2    = (float*)(ws + 71602048);                 // 400,000
  float* ad2    = (float*)(ws + 72002048);                 // 400,000
  unsigned short* W1tg = (unsigned short*)(ws + 72402048); // 65,536
  float* W2t    = (float*)(ws + 72467584);                 // 32,768
  float* wt     = (float*)(ws + 72500352);                 // 51,200,000 (dead after agg1)
  float* h3     = (float*)(ws + 72500352);                 // 12,800,000 (overlay)

  const int nb_scan = (NN + 255) / 256;  // 391

  k_zero<<<nb_scan, 256, 0, stream>>>((unsigned int*)counts, NN);
  k_prep<<<288, 256, 0, stream>>>(W1, W2, W1tg, W2t);

  dim3 g1((NN + 63) / 64, 2);
  k_gemm1<<<g1, 256, 0, stream>>>(x, W1tg, att_src1, att_dst1, h1b, as1, ad1);

  k_count<<<(EE + 255) / 256, 256, 0, stream>>>(ei, counts);
  k_scan1<<<nb_scan, 256, 0, stream>>>(counts, offs, bsums);
  k_scan2<<<1, 512, 0, stream>>>(bsums, nb_scan);
  k_scan3<<<nb_scan, 256, 0, stream>>>(offs, bsums, cursor);
  k_scatter<<<(EE + 255) / 256, 256, 0, stream>>>(ei, cursor, as1, ad1, esrc, wt);

  k_agg1<<<NN / 4, 256, 0, stream>>>(h1b, as1, ad1, offs, esrc, wt, b1, W2t,
                                     att_src2, att_dst2, h2b, as2, ad2);

  k_agg2<<<NN / 8, 256, 0, stream>>>(h2b, as2, ad2, offs, esrc, b2, h3);
  k_poolfin<<<GG, 256, 0, stream>>>(h3, batch, Wlin, blin, out);
}

// Round 9
// 689.965 us; speedup vs baseline: 1.3245x; 1.3245x over previous
//
#include <hip/hip_runtime.h>
#include <cstdint>

#define NN 100000
#define EE 1600000
#define GG 64
#define FIN 128
#define HC 256      // H*C for layer 1
#define NC 10

typedef short v8s __attribute__((ext_vector_type(8)));
typedef float v4f __attribute__((ext_vector_type(4)));

static __device__ __forceinline__ float lrelu(float x) { return x > 0.f ? x : 0.2f * x; }
static __device__ __forceinline__ float bf2f(unsigned short b) {
  return __uint_as_float(((unsigned int)b) << 16);
}
static __device__ __forceinline__ unsigned short f2bf(float f) {
  unsigned int u = __float_as_uint(f);
  unsigned int r = (u + 0x7FFFu + ((u >> 16) & 1u)) >> 16;
  return (unsigned short)r;
}
static __device__ __forceinline__ void unpack2(unsigned int u, float& f0, float& f1) {
  f0 = __uint_as_float(u << 16);          // even channel (lo ushort)
  f1 = __uint_as_float(u & 0xFFFF0000u);  // odd channel (hi ushort)
}

// ---------------- utility ----------------
__global__ void k_zero(unsigned int* __restrict__ p, int n) {
  int i = blockIdx.x * 256 + threadIdx.x;
  if (i < n) p[i] = 0u;
}

// ---------------- prep: W1 -> bf16 transposed [n][k] ----------------
__global__ void k_prep(const float* __restrict__ W1, unsigned short* __restrict__ W1tg) {
  const int b = blockIdx.x, t = threadIdx.x;
  if (t < 128) W1tg[b * 128 + t] = f2bf(W1[t * HC + b]);
}

// ---------------- GEMM1 (bf16 MFMA, LDS-free) + fused scores1 ----------------
// grid (1563, 2): 64 rows x 128-col half per block; 4 waves x 16 rows.
// B-fragments read directly from pre-transposed global W1tg (L2-hot, 64KB).
__global__ __launch_bounds__(256) void k_gemm1(const float* __restrict__ x,
                                               const unsigned short* __restrict__ W1tg,
                                               const float* __restrict__ att_src1,
                                               const float* __restrict__ att_dst1,
                                               unsigned short* __restrict__ h1b,
                                               float* __restrict__ as1,
                                               float* __restrict__ ad1) {
  const int t = threadIdx.x;
  const int m0 = blockIdx.x * 64;
  const int n0 = blockIdx.y * 128;
  const int hb = blockIdx.y * 4;       // head base of this column half
  const int lane = t & 63;
  const int wm = t >> 6;               // wave -> m sub-tile
  const int ml = lane & 15;
  const int quad = lane >> 4;
  int row = m0 + wm * 16 + ml; if (row >= NN) row = NN - 1;
  v4f acc[8];
#pragma unroll
  for (int tt = 0; tt < 8; ++tt) acc[tt] = (v4f){0.f, 0.f, 0.f, 0.f};
#pragma unroll
  for (int kk = 0; kk < 4; ++kk) {
    const int k0 = kk * 32 + quad * 8;
    float4 lo = *(const float4*)(x + (size_t)row * FIN + k0);
    float4 hi = *(const float4*)(x + (size_t)row * FIN + k0 + 4);
    v8s a;
    a[0] = (short)f2bf(lo.x); a[1] = (short)f2bf(lo.y);
    a[2] = (short)f2bf(lo.z); a[3] = (short)f2bf(lo.w);
    a[4] = (short)f2bf(hi.x); a[5] = (short)f2bf(hi.y);
    a[6] = (short)f2bf(hi.z); a[7] = (short)f2bf(hi.w);
#pragma unroll
    for (int tt = 0; tt < 8; ++tt) {
      v8s b = *(const v8s*)(W1tg + (size_t)(n0 + tt * 16 + ml) * FIN + k0);
      acc[tt] = __builtin_amdgcn_mfma_f32_16x16x32_bf16(a, b, acc[tt], 0, 0, 0);
    }
  }
  // h1b store (C layout: row=quad*4+r, col=tt*16+ml)
#pragma unroll
  for (int tt = 0; tt < 8; ++tt) {
#pragma unroll
    for (int r = 0; r < 4; ++r) {
      int rg = m0 + wm * 16 + quad * 4 + r;
      if (rg < NN) h1b[(size_t)rg * HC + n0 + tt * 16 + ml] = f2bf(acc[tt][r]);
    }
  }
  // fused scores1: 4 heads of this half; lane partials over its 8 columns
  float ps[4][4], pd[4][4];
#pragma unroll
  for (int i = 0; i < 4; ++i)
#pragma unroll
    for (int r = 0; r < 4; ++r) { ps[i][r] = 0.f; pd[i][r] = 0.f; }
#pragma unroll
  for (int i = 0; i < 4; ++i) {
#pragma unroll
    for (int half = 0; half < 2; ++half) {
      const int tt = 2 * i + half;
      const float a_s = att_src1[(hb + i) * 32 + half * 16 + ml];
      const float a_d = att_dst1[(hb + i) * 32 + half * 16 + ml];
#pragma unroll
      for (int r = 0; r < 4; ++r) {
        ps[i][r] += acc[tt][r] * a_s;
        pd[i][r] += acc[tt][r] * a_d;
      }
    }
  }
#pragma unroll
  for (int i = 0; i < 4; ++i) {
#pragma unroll
    for (int r = 0; r < 4; ++r) {
      float s = ps[i][r], d = pd[i][r];
      s += __shfl_xor(s, 1, 64); s += __shfl_xor(s, 2, 64);
      s += __shfl_xor(s, 4, 64); s += __shfl_xor(s, 8, 64);
      d += __shfl_xor(d, 1, 64); d += __shfl_xor(d, 2, 64);
      d += __shfl_xor(d, 4, 64); d += __shfl_xor(d, 8, 64);
      ps[i][r] = s; pd[i][r] = d;
    }
  }
  if (ml == 0) {
#pragma unroll
    for (int r = 0; r < 4; ++r) {
      int rg = m0 + wm * 16 + quad * 4 + r;
      if (rg < NN) {
#pragma unroll
        for (int i = 0; i < 4; ++i) {
          as1[rg * 8 + hb + i] = ps[i][r];
          ad1[rg * 8 + hb + i] = pd[i][r];
        }
      }
    }
  }
}

// ---------------- CSR build ----------------
__global__ void k_count(const int* __restrict__ ei, int* __restrict__ counts) {
  int e = blockIdx.x * 256 + threadIdx.x;
  if (e < EE) atomicAdd(&counts[ei[EE + e]], 1);
}

__global__ void k_scan1(const int* __restrict__ counts, int* __restrict__ offs,
                        int* __restrict__ bsums) {
  __shared__ int s[256];
  const int t = threadIdx.x;
  const int i = blockIdx.x * 256 + t;
  int v = (i < NN) ? counts[i] : 0;
  s[t] = v;
  __syncthreads();
  for (int off = 1; off < 256; off <<= 1) {
    int tv = (t >= off) ? s[t - off] : 0;
    __syncthreads();
    s[t] += tv;
    __syncthreads();
  }
  if (i < NN) offs[i] = s[t] - v;
  if (t == 255) bsums[blockIdx.x] = s[255];
}

__global__ void k_scan2(int* __restrict__ bsums, int nb) {
  __shared__ int s[512];
  const int t = threadIdx.x;
  int v = (t < nb) ? bsums[t] : 0;
  s[t] = v;
  __syncthreads();
  for (int off = 1; off < 512; off <<= 1) {
    int tv = (t >= off) ? s[t - off] : 0;
    __syncthreads();
    s[t] += tv;
    __syncthreads();
  }
  if (t < nb) bsums[t] = s[t] - v;
}

__global__ void k_scan3(int* __restrict__ offs, const int* __restrict__ bsums,
                        int* __restrict__ cursor) {
  const int i = blockIdx.x * 256 + threadIdx.x;
  if (i < NN) {
    int v = offs[i] + bsums[i >> 8];
    offs[i] = v;
    cursor[i] = v;
  }
  if (i == 0) offs[NN] = EE;
}

// ---------------- scatter + fused layer-1 edge weights ----------------
__global__ void k_scatter(const int* __restrict__ ei, int* __restrict__ cursor,
                          const float* __restrict__ as1, const float* __restrict__ ad1,
                          int* __restrict__ esrc, float* __restrict__ wt) {
  int e = blockIdx.x * 256 + threadIdx.x;
  if (e < EE) {
    int s = ei[e];
    int d = ei[EE + e];
    int p = atomicAdd(&cursor[d], 1);
    esrc[p] = s;
    float4 a0 = *(const float4*)(as1 + s * 8);
    float4 a1 = *(const float4*)(as1 + s * 8 + 4);
    float4 b0 = *(const float4*)(ad1 + d * 8);
    float4 b1 = *(const float4*)(ad1 + d * 8 + 4);
    float4 r0, r1;
    r0.x = __expf(lrelu(a0.x + b0.x)); r0.y = __expf(lrelu(a0.y + b0.y));
    r0.z = __expf(lrelu(a0.z + b0.z)); r0.w = __expf(lrelu(a0.w + b0.w));
    r1.x = __expf(lrelu(a1.x + b1.x)); r1.y = __expf(lrelu(a1.y + b1.y));
    r1.z = __expf(lrelu(a1.z + b1.z)); r1.w = __expf(lrelu(a1.w + b1.w));
    *(float4*)(wt + (size_t)p * 8) = r0;
    *(float4*)(wt + (size_t)p * 8 + 4) = r1;
  }
}

// ---------------- fused agg1 + bias + ELU + GEMM2 row + scores2 ----------------
// R7-proven structure: 128 threads (2 waves), TWO nodes per block, chunk-0
// index chains prefetched; gathers full 512B rows per wave (even/odd split).
__global__ __launch_bounds__(128) void k_agg1(const unsigned short* __restrict__ h1b,
                                              const float* __restrict__ as1,
                                              const float* __restrict__ ad1,
                                              const int* __restrict__ offs,
                                              const int* __restrict__ esrc,
                                              const float* __restrict__ wt,
                                              const float* __restrict__ b1,
                                              const float* __restrict__ W2,
                                              const float* __restrict__ att_src2,
                                              const float* __restrict__ att_dst2,
                                              unsigned short* __restrict__ h2b,
                                              float* __restrict__ as2,
                                              float* __restrict__ ad2) {
  __shared__ float wl[2][32][8];
  __shared__ float sv[256];
  __shared__ float zsh[2][8];
  __shared__ float sp[4][33];
  const int t = threadIdx.x;
  const int lane = t & 63;
  const int w = t >> 6;
  const int head = lane >> 3;
  const int n0 = blockIdx.x * 2;
  const int o0 = offs[n0], o1 = offs[n0 + 1], o2 = offs[n0 + 2];
  const uint2* h1u2 = (const uint2*)h1b;

  // prefetch chunk 0 of both nodes (index chain overlapped)
  int sreg[2] = {0, 0};
  const int cnt0 = min(32, o1 - o0);
  const int cnt1 = min(32, o2 - o1);
  if (lane < cnt0) sreg[0] = esrc[o0 + lane];
  if (lane < cnt1) sreg[1] = esrc[o1 + lane];
  {
    const int j = t >> 2, hh = (t & 3) * 2;
    if (j < cnt0) *(float2*)&wl[0][j][hh] = *(const float2*)(wt + (size_t)(o0 + j) * 8 + hh);
    if (j < cnt1) *(float2*)&wl[1][j][hh] = *(const float2*)(wt + (size_t)(o1 + j) * 8 + hh);
  }
  __syncthreads();

  for (int ns = 0; ns < 2; ++ns) {
    const int n = n0 + ns;
    const int sBeg = ns ? o1 : o0;
    const int sEnd = ns ? o2 : o1;
    float acc0 = 0.f, acc1 = 0.f, acc2 = 0.f, acc3 = 0.f, z = 0.f;
    if (w == 0) {   // self loop on wave 0
      float w0 = __expf(lrelu(as1[n * 8 + head] + ad1[n * 8 + head]));
      z = w0;
      uint2 q = h1u2[(size_t)n * 64 + lane];
      float f0, f1, f2, f3; unpack2(q.x, f0, f1); unpack2(q.y, f2, f3);
      acc0 = w0 * f0; acc1 = w0 * f1; acc2 = w0 * f2; acc3 = w0 * f3;
    }
    int sregc = sreg[ns];
    for (int base = sBeg; base < sEnd; base += 32) {
      const int cnt = min(32, sEnd - base);
      if (base != sBeg) {   // rare multi-chunk path: reload indices + weights
        sregc = 0;
        if (lane < cnt) sregc = esrc[base + lane];
        __syncthreads();
        const int j = t >> 2, hh = (t & 3) * 2;
        if (j < cnt) *(float2*)&wl[ns][j][hh] = *(const float2*)(wt + (size_t)(base + j) * 8 + hh);
        __syncthreads();
      }
#pragma unroll 8
      for (int j2 = w; j2 < cnt; j2 += 2) {
        int sj = __builtin_amdgcn_readlane(sregc, j2);   // uniform -> SGPR base
        uint2 q = h1u2[(size_t)sj * 64 + lane];          // full 512B row per wave
        float wv = wl[ns][j2][head];
        float f0, f1, f2, f3; unpack2(q.x, f0, f1); unpack2(q.y, f2, f3);
        z += wv;
        acc0 += wv * f0; acc1 += wv * f1; acc2 += wv * f2; acc3 += wv * f3;
      }
    }

    __syncthreads();
    if (w == 0) {
      *(float4*)&sv[4 * lane] = make_float4(acc0, acc1, acc2, acc3);
      if ((lane & 7) == 0) zsh[0][head] = z;
    }
    __syncthreads();
    if (w == 1) {
      float4 p = *(float4*)&sv[4 * lane];
      p.x += acc0; p.y += acc1; p.z += acc2; p.w += acc3;
      *(float4*)&sv[4 * lane] = p;
      if ((lane & 7) == 0) zsh[1][head] = z;
    }
    __syncthreads();
    {  // out1 = sv/z + b1, ELU (thread t -> channels 2t, 2t+1)
      const int ho = t >> 4;
      const float zf = zsh[0][ho] + zsh[1][ho];
      const float zi = 1.0f / (zf + 1e-16f);
      float2 bb = *(const float2*)(b1 + 2 * t);
      float v0 = sv[2 * t] * zi + bb.x;
      float v1 = sv[2 * t + 1] * zi + bb.y;
      v0 = v0 > 0.f ? v0 : (__expf(v0) - 1.0f);
      v1 = v1 > 0.f ? v1 : (__expf(v1) - 1.0f);
      __syncthreads();
      sv[2 * t] = v0; sv[2 * t + 1] = v1;
    }
    __syncthreads();
    // GEMM2 row: 4 k-slices of 64, c = output channel
    const int c = t & 31, rr = t >> 5;
    const float* svp = sv + rr * 64;
    const float* w2p = W2 + rr * 64 * 32 + c;
    float p = 0.f;
#pragma unroll 16
    for (int kk = 0; kk < 64; ++kk) p += svp[kk] * w2p[kk * 32];
    sp[rr][c] = p;
    __syncthreads();
    if (t < 32) {
      float hv = sp[0][t] + sp[1][t] + sp[2][t] + sp[3][t];
      h2b[(size_t)n * 32 + t] = f2bf(hv);
      float ps = hv * att_src2[t];
      float pd = hv * att_dst2[t];
#pragma unroll
      for (int m = 16; m >= 1; m >>= 1) {
        ps += __shfl_xor(ps, m, 64);
        pd += __shfl_xor(pd, m, 64);
      }
      if (t == 0) { as2[n] = ps; ad2[n] = pd; }
    }
    __syncthreads();   // protect sv/zsh/sp before next node
  }
}

// ---------------- agg2: softmax-weighted sum -> dense h3 ----------------
__global__ __launch_bounds__(256) void k_agg2(const unsigned short* __restrict__ h2b,
                                              const float* __restrict__ as2,
                                              const float* __restrict__ ad2,
                                              const int* __restrict__ offs,
                                              const int* __restrict__ esrc,
                                              const float* __restrict__ b2,
                                              float* __restrict__ h3) {
  const int t = threadIdx.x;
  const int g = t >> 5, c = t & 31;
  const int n = blockIdx.x * 8 + g;
  const int sbase = t & 32;
  const int start = offs[n], end = offs[n + 1];
  const float adn = ad2[n];
  float w0 = __expf(lrelu(as2[n] + adn));
  float z = w0;
  float acc = w0 * bf2f(h2b[(size_t)n * 32 + c]);
  for (int base = start; base < end; base += 32) {
    const int cnt = min(32, end - base);
    int s_reg = 0; float w_reg = 0.f;
    if (c < cnt) {
      s_reg = esrc[base + c];
      w_reg = __expf(lrelu(as2[s_reg] + adn));
    }
#pragma unroll 8
    for (int j = 0; j < cnt; ++j) {
      int sj = __shfl(s_reg, sbase + j, 64);
      float wj = __shfl(w_reg, sbase + j, 64);
      z += wj;
      acc += wj * bf2f(h2b[(size_t)sj * 32 + c]);
    }
  }
  h3[(size_t)n * 32 + c] = acc / (z + 1e-16f) + b2[c];
}

// ---------------- pool + final linear (fused) ----------------
__global__ __launch_bounds__(256) void k_poolfin(const float* __restrict__ h3,
                                                 const int* __restrict__ batch,
                                                 const float* __restrict__ Wlin,
                                                 const float* __restrict__ blin,
                                                 float* __restrict__ out) {
  __shared__ int bounds[2];
  __shared__ float red[8][33];
  __shared__ float mean[32];
  const int g = blockIdx.x;
  const int t = threadIdx.x;
  if (t < 2) {
    int target = g + t;
    int lo = 0, hi = NN;
    while (lo < hi) { int mid = (lo + hi) >> 1; if (batch[mid] < target) lo = mid + 1; else hi = mid; }
    bounds[t] = lo;
  }
  __syncthreads();
  const int lo = bounds[0], hi = bounds[1];
  const int rr = t >> 5, c = t & 31;
  float a = 0.f;
  for (int r = lo + rr; r < hi; r += 8) a += h3[(size_t)r * 32 + c];
  red[rr][c] = a;
  __syncthreads();
  if (rr == 0) {
    float s = 0.f;
#pragma unroll
    for (int i = 0; i < 8; ++i) s += red[i][c];
    float ct = (float)(hi - lo);
    ct = ct > 1.f ? ct : 1.f;
    mean[c] = s / ct;
  }
  __syncthreads();
  if (t < NC) {
    float acc = 0.f;
#pragma unroll
    for (int cc = 0; cc < 32; ++cc) acc += mean[cc] * Wlin[cc * NC + t];
    out[g * NC + t] = acc + blin[t];
  }
}

extern "C" void kernel_launch(void* const* d_in, const int* in_sizes, int n_in,
                              void* d_out, int out_size, void* d_ws, size_t ws_size,
                              hipStream_t stream) {
  const float* x        = (const float*)d_in[0];
  const int*   ei       = (const int*)d_in[1];
  const int*   batch    = (const int*)d_in[2];
  const float* W1       = (const float*)d_in[3];
  const float* att_src1 = (const float*)d_in[4];
  const float* att_dst1 = (const float*)d_in[5];
  const float* b1       = (const float*)d_in[6];
  const float* W2       = (const float*)d_in[7];
  const float* att_src2 = (const float*)d_in[8];
  const float* att_dst2 = (const float*)d_in[9];
  const float* b2       = (const float*)d_in[10];
  const float* Wlin     = (const float*)d_in[11];
  const float* blin     = (const float*)d_in[12];
  float* out = (float*)d_out;
  char* ws = (char*)d_ws;

  // workspace layout (bytes); peak ~124 MB (wt dead after agg1 -> h3 overlay)
  unsigned short* h1b  = (unsigned short*)(ws + 0);        // 51,200,000
  float* as1    = (float*)(ws + 51200000);                 // 3,200,000
  float* ad1    = (float*)(ws + 54400000);                 // 3,200,000
  int* counts   = (int*)(ws + 57600000);                   // 400,000
  int* offs     = (int*)(ws + 58000000);                   // 400,004 (+pad)
  int* cursor   = (int*)(ws + 58400256);                   // 400,000
  int* esrc     = (int*)(ws + 58800256);                   // 6,400,000
  int* bsums    = (int*)(ws + 65200256);                   // 1,564 (+pad)
  unsigned short* h2b = (unsigned short*)(ws + 65202048);  // 6,400,000
  float* as2    = (float*)(ws + 71602048);                 // 400,000
  float* ad2    = (float*)(ws + 72002048);                 // 400,000
  unsigned short* W1tg = (unsigned short*)(ws + 72402048); // 65,536
  float* wt     = (float*)(ws + 72467584);                 // 51,200,000 (dead after agg1)
  float* h3     = (float*)(ws + 72467584);                 // 12,800,000 (overlay)

  const int nb_scan = (NN + 255) / 256;  // 391

  k_zero<<<nb_scan, 256, 0, stream>>>((unsigned int*)counts, NN);
  k_prep<<<256, 128, 0, stream>>>(W1, W1tg);

  dim3 g1((NN + 63) / 64, 2);
  k_gemm1<<<g1, 256, 0, stream>>>(x, W1tg, att_src1, att_dst1, h1b, as1, ad1);

  k_count<<<(EE + 255) / 256, 256, 0, stream>>>(ei, counts);
  k_scan1<<<nb_scan, 256, 0, stream>>>(counts, offs, bsums);
  k_scan2<<<1, 512, 0, stream>>>(bsums, nb_scan);
  k_scan3<<<nb_scan, 256, 0, stream>>>(offs, bsums, cursor);
  k_scatter<<<(EE + 255) / 256, 256, 0, stream>>>(ei, cursor, as1, ad1, esrc, wt);

  k_agg1<<<NN / 2, 128, 0, stream>>>(h1b, as1, ad1, offs, esrc, wt, b1, W2,
                                     att_src2, att_dst2, h2b, as2, ad2);

  k_agg2<<<NN / 8, 256, 0, stream>>>(h2b, as2, ad2, offs, esrc, b2, h3);
  k_poolfin<<<GG, 256, 0, stream>>>(h3, batch, Wlin, blin, out);
}

// Round 10
// 667.395 us; speedup vs baseline: 1.3693x; 1.0338x over previous
//
#include <hip/hip_runtime.h>
#include <cstdint>

#define NN 100000
#define EE 1600000
#define GG 64
#define FIN 128
#define HC 256      // H*C for layer 1
#define NC 10

typedef short v8s __attribute__((ext_vector_type(8)));
typedef float v4f __attribute__((ext_vector_type(4)));

static __device__ __forceinline__ float lrelu(float x) { return x > 0.f ? x : 0.2f * x; }
static __device__ __forceinline__ float bf2f(unsigned short b) {
  return __uint_as_float(((unsigned int)b) << 16);
}
static __device__ __forceinline__ unsigned short f2bf(float f) {
  unsigned int u = __float_as_uint(f);
  unsigned int r = (u + 0x7FFFu + ((u >> 16) & 1u)) >> 16;
  return (unsigned short)r;
}
static __device__ __forceinline__ unsigned int pk2bf(float a, float b) {
  return (unsigned int)f2bf(a) | ((unsigned int)f2bf(b) << 16);
}
static __device__ __forceinline__ void unpack2(unsigned int u, float& f0, float& f1) {
  f0 = __uint_as_float(u << 16);          // even channel (lo ushort)
  f1 = __uint_as_float(u & 0xFFFF0000u);  // odd channel (hi ushort)
}

// ---------------- prepx: x -> bf16 (streamed) + zero counts ----------------
__global__ __launch_bounds__(256) void k_prepx(const float* __restrict__ x,
                                               unsigned short* __restrict__ xb,
                                               unsigned int* __restrict__ counts) {
  const int idx = blockIdx.x * 256 + threadIdx.x;
  const int i4 = idx * 4;                       // 12500*256*4 == 12.8M exact
  float4 v = *(const float4*)(x + i4);
  ushort4 u;
  u.x = f2bf(v.x); u.y = f2bf(v.y); u.z = f2bf(v.z); u.w = f2bf(v.w);
  *(ushort4*)(xb + i4) = u;
  if (idx < NN) counts[idx] = 0u;
}

// ---------------- prep: W1 -> bf16 transposed [n][k] ----------------
__global__ void k_prep(const float* __restrict__ W1, unsigned short* __restrict__ W1tg) {
  const int b = blockIdx.x, t = threadIdx.x;
  if (t < 128) W1tg[b * 128 + t] = f2bf(W1[t * HC + b]);
}

// ---------------- GEMM1 (bf16 MFMA, LDS-free) + fused scores1 ----------------
// grid (1563, 2): 64 rows x 128-col half per block; 4 waves x 16 rows.
// A-fragments from pre-converted xb; B-fragments from pre-transposed W1tg.
__global__ __launch_bounds__(256) void k_gemm1(const unsigned short* __restrict__ xb,
                                               const unsigned short* __restrict__ W1tg,
                                               const float* __restrict__ att_src1,
                                               const float* __restrict__ att_dst1,
                                               unsigned short* __restrict__ h1b,
                                               float* __restrict__ as1,
                                               float* __restrict__ ad1) {
  const int t = threadIdx.x;
  const int m0 = blockIdx.x * 64;
  const int n0 = blockIdx.y * 128;
  const int hb = blockIdx.y * 4;       // head base of this column half
  const int lane = t & 63;
  const int wm = t >> 6;               // wave -> m sub-tile
  const int ml = lane & 15;
  const int quad = lane >> 4;
  int row = m0 + wm * 16 + ml; if (row >= NN) row = NN - 1;
  v4f acc[8];
#pragma unroll
  for (int tt = 0; tt < 8; ++tt) acc[tt] = (v4f){0.f, 0.f, 0.f, 0.f};
#pragma unroll
  for (int kk = 0; kk < 4; ++kk) {
    const int k0 = kk * 32 + quad * 8;
    v8s a = *(const v8s*)(xb + (size_t)row * FIN + k0);
#pragma unroll
    for (int tt = 0; tt < 8; ++tt) {
      v8s b = *(const v8s*)(W1tg + (size_t)(n0 + tt * 16 + ml) * FIN + k0);
      acc[tt] = __builtin_amdgcn_mfma_f32_16x16x32_bf16(a, b, acc[tt], 0, 0, 0);
    }
  }
  // h1b store (C layout: row=quad*4+r, col=tt*16+ml)
#pragma unroll
  for (int tt = 0; tt < 8; ++tt) {
#pragma unroll
    for (int r = 0; r < 4; ++r) {
      int rg = m0 + wm * 16 + quad * 4 + r;
      if (rg < NN) h1b[(size_t)rg * HC + n0 + tt * 16 + ml] = f2bf(acc[tt][r]);
    }
  }
  // fused scores1: 4 heads of this half; lane partials over its 8 columns
  float ps[4][4], pd[4][4];
#pragma unroll
  for (int i = 0; i < 4; ++i)
#pragma unroll
    for (int r = 0; r < 4; ++r) { ps[i][r] = 0.f; pd[i][r] = 0.f; }
#pragma unroll
  for (int i = 0; i < 4; ++i) {
#pragma unroll
    for (int half = 0; half < 2; ++half) {
      const int tt = 2 * i + half;
      const float a_s = att_src1[(hb + i) * 32 + half * 16 + ml];
      const float a_d = att_dst1[(hb + i) * 32 + half * 16 + ml];
#pragma unroll
      for (int r = 0; r < 4; ++r) {
        ps[i][r] += acc[tt][r] * a_s;
        pd[i][r] += acc[tt][r] * a_d;
      }
    }
  }
#pragma unroll
  for (int i = 0; i < 4; ++i) {
#pragma unroll
    for (int r = 0; r < 4; ++r) {
      float s = ps[i][r], d = pd[i][r];
      s += __shfl_xor(s, 1, 64); s += __shfl_xor(s, 2, 64);
      s += __shfl_xor(s, 4, 64); s += __shfl_xor(s, 8, 64);
      d += __shfl_xor(d, 1, 64); d += __shfl_xor(d, 2, 64);
      d += __shfl_xor(d, 4, 64); d += __shfl_xor(d, 8, 64);
      ps[i][r] = s; pd[i][r] = d;
    }
  }
  if (ml == 0) {
#pragma unroll
    for (int r = 0; r < 4; ++r) {
      int rg = m0 + wm * 16 + quad * 4 + r;
      if (rg < NN) {
#pragma unroll
        for (int i = 0; i < 4; ++i) {
          as1[rg * 8 + hb + i] = ps[i][r];
          ad1[rg * 8 + hb + i] = pd[i][r];
        }
      }
    }
  }
}

// ---------------- CSR build ----------------
__global__ void k_count(const int* __restrict__ ei, int* __restrict__ counts) {
  int e = blockIdx.x * 256 + threadIdx.x;
  if (e < EE) atomicAdd(&counts[ei[EE + e]], 1);
}

__global__ void k_scan1(const int* __restrict__ counts, int* __restrict__ offs,
                        int* __restrict__ bsums) {
  __shared__ int s[256];
  const int t = threadIdx.x;
  const int i = blockIdx.x * 256 + t;
  int v = (i < NN) ? counts[i] : 0;
  s[t] = v;
  __syncthreads();
  for (int off = 1; off < 256; off <<= 1) {
    int tv = (t >= off) ? s[t - off] : 0;
    __syncthreads();
    s[t] += tv;
    __syncthreads();
  }
  if (i < NN) offs[i] = s[t] - v;
  if (t == 255) bsums[blockIdx.x] = s[255];
}

__global__ void k_scan2(int* __restrict__ bsums, int nb) {
  __shared__ int s[512];
  const int t = threadIdx.x;
  int v = (t < nb) ? bsums[t] : 0;
  s[t] = v;
  __syncthreads();
  for (int off = 1; off < 512; off <<= 1) {
    int tv = (t >= off) ? s[t - off] : 0;
    __syncthreads();
    s[t] += tv;
    __syncthreads();
  }
  if (t < nb) bsums[t] = s[t] - v;
}

__global__ void k_scan3(int* __restrict__ offs, const int* __restrict__ bsums,
                        int* __restrict__ cursor) {
  const int i = blockIdx.x * 256 + threadIdx.x;
  if (i < NN) {
    int v = offs[i] + bsums[i >> 8];
    offs[i] = v;
    cursor[i] = v;
  }
  if (i == 0) offs[NN] = EE;
}

// ---------------- scatter + fused layer-1 edge weights (bf16 packed) ----------------
__global__ void k_scatter(const int* __restrict__ ei, int* __restrict__ cursor,
                          const float* __restrict__ as1, const float* __restrict__ ad1,
                          int* __restrict__ esrc, uint4* __restrict__ wt16) {
  int e = blockIdx.x * 256 + threadIdx.x;
  if (e < EE) {
    int s = ei[e];
    int d = ei[EE + e];
    int p = atomicAdd(&cursor[d], 1);
    esrc[p] = s;
    float4 a0 = *(const float4*)(as1 + s * 8);
    float4 a1 = *(const float4*)(as1 + s * 8 + 4);
    float4 b0 = *(const float4*)(ad1 + d * 8);
    float4 b1 = *(const float4*)(ad1 + d * 8 + 4);
    uint4 u;
    u.x = pk2bf(__expf(lrelu(a0.x + b0.x)), __expf(lrelu(a0.y + b0.y)));
    u.y = pk2bf(__expf(lrelu(a0.z + b0.z)), __expf(lrelu(a0.w + b0.w)));
    u.z = pk2bf(__expf(lrelu(a1.x + b1.x)), __expf(lrelu(a1.y + b1.y)));
    u.w = pk2bf(__expf(lrelu(a1.z + b1.z)), __expf(lrelu(a1.w + b1.w)));
    wt16[p] = u;
  }
}

// ---------------- fused agg1 + bias + ELU + GEMM2 row + scores2 ----------------
// R7/R9-proven structure: 128 threads (2 waves), TWO nodes per block, chunk-0
// index chains prefetched; gathers full 512B rows per wave (even/odd split).
// wt now bf16-packed: 4 threads/edge load uint (2 weights) -> unpack -> wl.
__global__ __launch_bounds__(128) void k_agg1(const unsigned short* __restrict__ h1b,
                                              const float* __restrict__ as1,
                                              const float* __restrict__ ad1,
                                              const int* __restrict__ offs,
                                              const int* __restrict__ esrc,
                                              const unsigned int* __restrict__ wt4,
                                              const float* __restrict__ b1,
                                              const float* __restrict__ W2,
                                              const float* __restrict__ att_src2,
                                              const float* __restrict__ att_dst2,
                                              unsigned short* __restrict__ h2b,
                                              float* __restrict__ as2,
                                              float* __restrict__ ad2) {
  __shared__ float wl[2][32][8];
  __shared__ float sv[256];
  __shared__ float zsh[2][8];
  __shared__ float sp[4][33];
  const int t = threadIdx.x;
  const int lane = t & 63;
  const int w = t >> 6;
  const int head = lane >> 3;
  const int n0 = blockIdx.x * 2;
  const int o0 = offs[n0], o1 = offs[n0 + 1], o2 = offs[n0 + 2];
  const uint2* h1u2 = (const uint2*)h1b;

  // prefetch chunk 0 of both nodes (index chain overlapped)
  int sreg[2] = {0, 0};
  const int cnt0 = min(32, o1 - o0);
  const int cnt1 = min(32, o2 - o1);
  if (lane < cnt0) sreg[0] = esrc[o0 + lane];
  if (lane < cnt1) sreg[1] = esrc[o1 + lane];
  {
    const int j = t >> 2, hq = t & 3;
    if (j < cnt0) {
      float f0, f1; unpack2(wt4[(size_t)(o0 + j) * 4 + hq], f0, f1);
      *(float2*)&wl[0][j][hq * 2] = make_float2(f0, f1);
    }
    if (j < cnt1) {
      float f0, f1; unpack2(wt4[(size_t)(o1 + j) * 4 + hq], f0, f1);
      *(float2*)&wl[1][j][hq * 2] = make_float2(f0, f1);
    }
  }
  __syncthreads();

  for (int ns = 0; ns < 2; ++ns) {
    const int n = n0 + ns;
    const int sBeg = ns ? o1 : o0;
    const int sEnd = ns ? o2 : o1;
    float acc0 = 0.f, acc1 = 0.f, acc2 = 0.f, acc3 = 0.f, z = 0.f;
    if (w == 0) {   // self loop on wave 0
      float w0 = __expf(lrelu(as1[n * 8 + head] + ad1[n * 8 + head]));
      z = w0;
      uint2 q = h1u2[(size_t)n * 64 + lane];
      float f0, f1, f2, f3; unpack2(q.x, f0, f1); unpack2(q.y, f2, f3);
      acc0 = w0 * f0; acc1 = w0 * f1; acc2 = w0 * f2; acc3 = w0 * f3;
    }
    int sregc = sreg[ns];
    for (int base = sBeg; base < sEnd; base += 32) {
      const int cnt = min(32, sEnd - base);
      if (base != sBeg) {   // rare multi-chunk path: reload indices + weights
        sregc = 0;
        if (lane < cnt) sregc = esrc[base + lane];
        __syncthreads();
        const int j = t >> 2, hq = t & 3;
        if (j < cnt) {
          float f0, f1; unpack2(wt4[(size_t)(base + j) * 4 + hq], f0, f1);
          *(float2*)&wl[ns][j][hq * 2] = make_float2(f0, f1);
        }
        __syncthreads();
      }
#pragma unroll 8
      for (int j2 = w; j2 < cnt; j2 += 2) {
        int sj = __builtin_amdgcn_readlane(sregc, j2);   // uniform -> SGPR base
        uint2 q = h1u2[(size_t)sj * 64 + lane];          // full 512B row per wave
        float wv = wl[ns][j2][head];
        float f0, f1, f2, f3; unpack2(q.x, f0, f1); unpack2(q.y, f2, f3);
        z += wv;
        acc0 += wv * f0; acc1 += wv * f1; acc2 += wv * f2; acc3 += wv * f3;
      }
    }

    __syncthreads();
    if (w == 0) {
      *(float4*)&sv[4 * lane] = make_float4(acc0, acc1, acc2, acc3);
      if ((lane & 7) == 0) zsh[0][head] = z;
    }
    __syncthreads();
    if (w == 1) {
      float4 p = *(float4*)&sv[4 * lane];
      p.x += acc0; p.y += acc1; p.z += acc2; p.w += acc3;
      *(float4*)&sv[4 * lane] = p;
      if ((lane & 7) == 0) zsh[1][head] = z;
    }
    __syncthreads();
    {  // out1 = sv/z + b1, ELU (thread t -> channels 2t, 2t+1)
      const int ho = t >> 4;
      const float zf = zsh[0][ho] + zsh[1][ho];
      const float zi = 1.0f / (zf + 1e-16f);
      float2 bb = *(const float2*)(b1 + 2 * t);
      float v0 = sv[2 * t] * zi + bb.x;
      float v1 = sv[2 * t + 1] * zi + bb.y;
      v0 = v0 > 0.f ? v0 : (__expf(v0) - 1.0f);
      v1 = v1 > 0.f ? v1 : (__expf(v1) - 1.0f);
      __syncthreads();
      sv[2 * t] = v0; sv[2 * t + 1] = v1;
    }
    __syncthreads();
    // GEMM2 row: 4 k-slices of 64, c = output channel
    const int c = t & 31, rr = t >> 5;
    const float* svp = sv + rr * 64;
    const float* w2p = W2 + rr * 64 * 32 + c;
    float p = 0.f;
#pragma unroll 16
    for (int kk = 0; kk < 64; ++kk) p += svp[kk] * w2p[kk * 32];
    sp[rr][c] = p;
    __syncthreads();
    if (t < 32) {
      float hv = sp[0][t] + sp[1][t] + sp[2][t] + sp[3][t];
      h2b[(size_t)n * 32 + t] = f2bf(hv);
      float ps = hv * att_src2[t];
      float pd = hv * att_dst2[t];
#pragma unroll
      for (int m = 16; m >= 1; m >>= 1) {
        ps += __shfl_xor(ps, m, 64);
        pd += __shfl_xor(pd, m, 64);
      }
      if (t == 0) { as2[n] = ps; ad2[n] = pd; }
    }
    __syncthreads();   // protect sv/zsh/sp before next node
  }
}

// ---------------- agg2: wave-per-node, 4 edges/iter, uint loads ----------------
// lane = slot(0..3)*16 + col(0..15); col covers channel pair (2col, 2col+1).
// 4 edges processed concurrently by the 4 slot groups; slot-reduce at end.
__global__ __launch_bounds__(256) void k_agg2(const unsigned short* __restrict__ h2b,
                                              const float* __restrict__ as2,
                                              const float* __restrict__ ad2,
                                              const int* __restrict__ offs,
                                              const int* __restrict__ esrc,
                                              const float* __restrict__ b2,
                                              float* __restrict__ h3) {
  const int t = threadIdx.x;
  const int lane = t & 63;
  const int wv = t >> 6;
  const int n = blockIdx.x * 4 + wv;     // NN = 25000*4 exactly
  const int col = lane & 15;
  const int slot = lane >> 4;
  const unsigned int* h2u = (const unsigned int*)h2b;
  const int start = offs[n], end = offs[n + 1];
  const float adn = ad2[n];
  float z = 0.f, acc0 = 0.f, acc1 = 0.f;
  if (slot == 0) {   // self loop counted once
    float w0 = __expf(lrelu(as2[n] + adn));
    unsigned int q = h2u[(size_t)n * 16 + col];
    float f0, f1; unpack2(q, f0, f1);
    z = w0; acc0 = w0 * f0; acc1 = w0 * f1;
  }
  for (int base = start; base < end; base += 64) {
    const int cnt = min(64, end - base);
    int sreg = 0; float wreg = 0.f;
    if (lane < cnt) {
      sreg = esrc[base + lane];
      wreg = __expf(lrelu(as2[sreg] + adn));
    }
    const int jmax = (cnt + 3) >> 2;
#pragma unroll 4
    for (int j = 0; j < jmax; ++j) {
      const int e = 4 * j + slot;
      int sj = __shfl(sreg, e, 64);      // per-lane src (bpermute)
      float wj = __shfl(wreg, e, 64);
      if (e < cnt) {
        unsigned int q = h2u[(size_t)sj * 16 + col];
        float f0, f1; unpack2(q, f0, f1);
        z += wj; acc0 += wj * f0; acc1 += wj * f1;
      }
    }
  }
  // combine the 4 slot groups
  acc0 += __shfl_xor(acc0, 16, 64); acc0 += __shfl_xor(acc0, 32, 64);
  acc1 += __shfl_xor(acc1, 16, 64); acc1 += __shfl_xor(acc1, 32, 64);
  z    += __shfl_xor(z, 16, 64);    z    += __shfl_xor(z, 32, 64);
  if (slot == 0) {
    const float zi = 1.0f / (z + 1e-16f);
    float2 bb = *(const float2*)(b2 + 2 * col);
    float2 o;
    o.x = acc0 * zi + bb.x;
    o.y = acc1 * zi + bb.y;
    *(float2*)(h3 + (size_t)n * 32 + 2 * col) = o;
  }
}

// ---------------- pool + final linear (fused) ----------------
__global__ __launch_bounds__(256) void k_poolfin(const float* __restrict__ h3,
                                                 const int* __restrict__ batch,
                                                 const float* __restrict__ Wlin,
                                                 const float* __restrict__ blin,
                                                 float* __restrict__ out) {
  __shared__ int bounds[2];
  __shared__ float red[8][33];
  __shared__ float mean[32];
  const int g = blockIdx.x;
  const int t = threadIdx.x;
  if (t < 2) {
    int target = g + t;
    int lo = 0, hi = NN;
    while (lo < hi) { int mid = (lo + hi) >> 1; if (batch[mid] < target) lo = mid + 1; else hi = mid; }
    bounds[t] = lo;
  }
  __syncthreads();
  const int lo = bounds[0], hi = bounds[1];
  const int rr = t >> 5, c = t & 31;
  float a = 0.f;
  for (int r = lo + rr; r < hi; r += 8) a += h3[(size_t)r * 32 + c];
  red[rr][c] = a;
  __syncthreads();
  if (rr == 0) {
    float s = 0.f;
#pragma unroll
    for (int i = 0; i < 8; ++i) s += red[i][c];
    float ct = (float)(hi - lo);
    ct = ct > 1.f ? ct : 1.f;
    mean[c] = s / ct;
  }
  __syncthreads();
  if (t < NC) {
    float acc = 0.f;
#pragma unroll
    for (int cc = 0; cc < 32; ++cc) acc += mean[cc] * Wlin[cc * NC + t];
    out[g * NC + t] = acc + blin[t];
  }
}

extern "C" void kernel_launch(void* const* d_in, const int* in_sizes, int n_in,
                              void* d_out, int out_size, void* d_ws, size_t ws_size,
                              hipStream_t stream) {
  const float* x        = (const float*)d_in[0];
  const int*   ei       = (const int*)d_in[1];
  const int*   batch    = (const int*)d_in[2];
  const float* W1       = (const float*)d_in[3];
  const float* att_src1 = (const float*)d_in[4];
  const float* att_dst1 = (const float*)d_in[5];
  const float* b1       = (const float*)d_in[6];
  const float* W2       = (const float*)d_in[7];
  const float* att_src2 = (const float*)d_in[8];
  const float* att_dst2 = (const float*)d_in[9];
  const float* b2       = (const float*)d_in[10];
  const float* Wlin     = (const float*)d_in[11];
  const float* blin     = (const float*)d_in[12];
  float* out = (float*)d_out;
  char* ws = (char*)d_ws;

  // workspace layout (bytes); peak ~124 MB (wt16 dead after agg1 -> h3 overlay)
  unsigned short* h1b  = (unsigned short*)(ws + 0);        // 51,200,000
  unsigned short* xb   = (unsigned short*)(ws + 51200000); // 25,600,000
  float* as1    = (float*)(ws + 76800000);                 // 3,200,000
  float* ad1    = (float*)(ws + 80000000);                 // 3,200,000
  int* counts   = (int*)(ws + 83200000);                   // 400,000
  int* offs     = (int*)(ws + 83600000);                   // 400,004 (+pad)
  int* cursor   = (int*)(ws + 84000256);                   // 400,000
  int* esrc     = (int*)(ws + 84400256);                   // 6,400,000
  int* bsums    = (int*)(ws + 90800256);                   // 1,564 (+pad)
  unsigned short* h2b = (unsigned short*)(ws + 90802048);  // 6,400,000
  float* as2    = (float*)(ws + 97202048);                 // 400,000
  float* ad2    = (float*)(ws + 97602048);                 // 400,000
  unsigned short* W1tg = (unsigned short*)(ws + 98002048); // 65,536
  uint4* wt16   = (uint4*)(ws + 98067584);                 // 25,600,000 (dead after agg1)
  float* h3     = (float*)(ws + 98067584);                 // 12,800,000 (overlay)

  const int nb_scan = (NN + 255) / 256;  // 391

  k_prepx<<<12500, 256, 0, stream>>>(x, xb, (unsigned int*)counts);
  k_prep<<<256, 128, 0, stream>>>(W1, W1tg);

  dim3 g1((NN + 63) / 64, 2);
  k_gemm1<<<g1, 256, 0, stream>>>(xb, W1tg, att_src1, att_dst1, h1b, as1, ad1);

  k_count<<<(EE + 255) / 256, 256, 0, stream>>>(ei, counts);
  k_scan1<<<nb_scan, 256, 0, stream>>>(counts, offs, bsums);
  k_scan2<<<1, 512, 0, stream>>>(bsums, nb_scan);
  k_scan3<<<nb_scan, 256, 0, stream>>>(offs, bsums, cursor);
  k_scatter<<<(EE + 255) / 256, 256, 0, stream>>>(ei, cursor, as1, ad1, esrc, wt16);

  k_agg1<<<NN / 2, 128, 0, stream>>>(h1b, as1, ad1, offs, esrc, (const unsigned int*)wt16,
                                     b1, W2, att_src2, att_dst2, h2b, as2, ad2);

  k_agg2<<<NN / 4, 256, 0, stream>>>(h2b, as2, ad2, offs, esrc, b2, h3);
  k_poolfin<<<GG, 256, 0, stream>>>(h3, batch, Wlin, blin, out);
}